// Round 4
// baseline (270.845 us; speedup 1.0000x reference)
//
#include <hip/hip_runtime.h>
#include <stdint.h>

#define BS 4
#define SEQ 1024
#define DIM 1024
#define NH 16
#define DH 64
#define MROWS (BS*SEQ)   // 4096

#define MT 128
#define NT 64
#define KT 32
#define NBM (MROWS/MT)   // 32
#define NBN (DIM/NT)     // 16
#define NWG (NBM*NBN)    // 512
#define NKT (DIM/KT)     // 32

typedef __attribute__((ext_vector_type(8))) short bf16x8;
typedef __attribute__((ext_vector_type(4))) float f32x4;
typedef __attribute__((ext_vector_type(8))) unsigned short ushort8;
typedef __attribute__((ext_vector_type(4))) float float4v;

__device__ __forceinline__ unsigned short f2bf(float x) {
  union { float f; uint32_t u; } a; a.f = x;
  uint32_t r = (a.u + 0x7FFFu + ((a.u >> 16) & 1u)) >> 16;  // RNE
  return (unsigned short)r;
}

typedef const void __attribute__((address_space(1)))* gvp;
typedef void __attribute__((address_space(3)))* lvp;
__device__ __forceinline__ void gld_lds16(const void* g, void* l) {
  // async global->LDS, 16B/lane; LDS dest = wave-uniform base + lane*16
  __builtin_amdgcn_global_load_lds((gvp)g, (lvp)l, 16, 0, 0);
}

// ---------------- fp32 -> bf16 cast (query/key/value) ----------------
__global__ __launch_bounds__(256) void cast_qkv(
    const float* __restrict__ q, const float* __restrict__ k, const float* __restrict__ v,
    unsigned short* __restrict__ qo, unsigned short* __restrict__ ko, unsigned short* __restrict__ vo) {
  const float* s = blockIdx.y == 0 ? q : (blockIdx.y == 1 ? k : v);
  unsigned short* d = blockIdx.y == 0 ? qo : (blockIdx.y == 1 ? ko : vo);
  size_t i = ((size_t)blockIdx.x * 256 + threadIdx.x) * 8;
  float4v x0 = *(const float4v*)(s + i);
  float4v x1 = *(const float4v*)(s + i + 4);
  ushort8 r;
  r[0]=f2bf(x0[0]); r[1]=f2bf(x0[1]); r[2]=f2bf(x0[2]); r[3]=f2bf(x0[3]);
  r[4]=f2bf(x1[0]); r[5]=f2bf(x1[1]); r[6]=f2bf(x1[2]); r[7]=f2bf(x1[3]);
  *(ushort8*)(d + i) = r;
}

// ---------------- weight cast + transpose: WT[n][k] = bf16(W[k][n]) ----------------
__global__ __launch_bounds__(256) void wcast_t(
    const float* __restrict__ w0, const float* __restrict__ w1,
    const float* __restrict__ w2, const float* __restrict__ w3,
    unsigned short* __restrict__ t0, unsigned short* __restrict__ t1,
    unsigned short* __restrict__ t2, unsigned short* __restrict__ t3) {
  __shared__ float tile[32][33];
  const float* W = blockIdx.z == 0 ? w0 : blockIdx.z == 1 ? w1 : blockIdx.z == 2 ? w2 : w3;
  unsigned short* T = blockIdx.z == 0 ? t0 : blockIdx.z == 1 ? t1 : blockIdx.z == 2 ? t2 : t3;
  int tx = threadIdx.x & 31, ty = threadIdx.x >> 5;   // 32 x 8
  int bx = blockIdx.x, by = blockIdx.y;
#pragma unroll
  for (int j = 0; j < 4; j++)
    tile[ty + 8*j][tx] = W[(size_t)(by*32 + ty + 8*j)*DIM + bx*32 + tx];
  __syncthreads();
#pragma unroll
  for (int j = 0; j < 4; j++)
    T[(size_t)(bx*32 + ty + 8*j)*DIM + by*32 + tx] = f2bf(tile[tx][ty + 8*j]);
}

// ---------------- GEMM core: C[M=4096,N=1024] = A @ BT^T (+bias) ----------------
// MODE 0: bf16 out, (acc+bias)*scale, natural [row][col]
// MODE 2: bf16 out, acc+bias, written transposed per head: VT[b][h][d][s]
// MODE 3: f32 out, acc+bias
template<int MODE>
__device__ __forceinline__ void gemm_core(
    unsigned short* lds,
    const unsigned short* __restrict__ A, const unsigned short* __restrict__ BT,
    const float* __restrict__ bias, void* __restrict__ outp, float scale) {
  unsigned short* Abase = lds;                 // 2 x MT*KT
  unsigned short* Bbase = lds + 2*MT*KT;       // 2 x NT*KT
  int id = blockIdx.x;
  int sw = (id & 7) * (NWG/8) + (id >> 3);     // XCD-aware swizzle (bijective, 512%8==0)
  int bm = sw & (NBM-1), bn = sw >> 5;
  int tid = threadIdx.x, w = tid >> 6, l = tid & 63;
  int wr = w >> 1, wc = w & 1;
  int lr = l & 15, lg = l >> 4;

  auto stage = [&](int buf, int kt) {
    const unsigned short* a0 = A + (size_t)(bm*MT + w*32 + (l>>2))*DIM + kt*KT + (l&3)*8;
    gld_lds16(a0,          Abase + buf*MT*KT + (w*32)*KT);
    gld_lds16(a0 + 16*DIM, Abase + buf*MT*KT + (w*32 + 16)*KT);
    const unsigned short* b0 = BT + (size_t)(bn*NT + w*16 + (l>>2))*DIM + kt*KT + (l&3)*8;
    gld_lds16(b0,          Bbase + buf*NT*KT + (w*16)*KT);
  };

  f32x4 acc[4][2] = {};
  int buf = 0;
  stage(0, 0);
  __syncthreads();
  for (int kt = 0; kt < NKT; kt++) {
    if (kt + 1 < NKT) stage(buf ^ 1, kt + 1);
    unsigned short* As = Abase + buf*MT*KT;
    unsigned short* Bs = Bbase + buf*NT*KT;
    bf16x8 af[4], bf_[2];
#pragma unroll
    for (int mi = 0; mi < 4; mi++)
      af[mi] = *(const bf16x8*)&As[(wr*64 + mi*16 + lr)*KT + lg*8];
#pragma unroll
    for (int ni = 0; ni < 2; ni++)
      bf_[ni] = *(const bf16x8*)&Bs[(wc*32 + ni*16 + lr)*KT + lg*8];
#pragma unroll
    for (int mi = 0; mi < 4; mi++)
#pragma unroll
      for (int ni = 0; ni < 2; ni++)
        acc[mi][ni] = __builtin_amdgcn_mfma_f32_16x16x32_bf16(af[mi], bf_[ni], acc[mi][ni], 0, 0, 0);
    __syncthreads();   // drains vmcnt for the staged next tile + protects buffer reuse
    buf ^= 1;
  }

  int row0 = bm*MT + wr*64;
  int col0 = bn*NT + wc*32;
#pragma unroll
  for (int ni = 0; ni < 2; ni++) {
    int col = col0 + ni*16 + lr;
    float bv = bias[col];
#pragma unroll
    for (int mi = 0; mi < 4; mi++)
#pragma unroll
      for (int r = 0; r < 4; r++) {
        int row = row0 + mi*16 + lg*4 + r;
        float val = acc[mi][ni][r] + bv;
        if (MODE == 0) {
          ((unsigned short*)outp)[(size_t)row*DIM + col] = f2bf(val * scale);
        } else if (MODE == 2) {
          int b = row >> 10, s = row & 1023, h = col >> 6, d = col & 63;
          ((unsigned short*)outp)[(size_t)((b*NH + h)*DH + d)*SEQ + s] = f2bf(val);
        } else {
          ((float*)outp)[(size_t)row*DIM + col] = val;
        }
      }
  }
}

__global__ __launch_bounds__(256) void qkv_gemm(
    const unsigned short* __restrict__ qb, const unsigned short* __restrict__ kb,
    const unsigned short* __restrict__ vb,
    const unsigned short* __restrict__ WqT, const unsigned short* __restrict__ WkT,
    const unsigned short* __restrict__ WvT,
    const float* __restrict__ bq, const float* __restrict__ bk, const float* __restrict__ bv,
    unsigned short* __restrict__ Qp, unsigned short* __restrict__ Kp,
    unsigned short* __restrict__ VT) {
  __shared__ __align__(16) unsigned short lds[2*(MT+NT)*KT];
  int z = blockIdx.y;
  if (z == 0)      gemm_core<0>(lds, qb, WqT, bq, Qp, 0.125f);   // 1/sqrt(64)
  else if (z == 1) gemm_core<0>(lds, kb, WkT, bk, Kp, 1.0f);
  else             gemm_core<2>(lds, vb, WvT, bv, VT, 1.0f);
}

__global__ __launch_bounds__(256) void out_gemm(
    const unsigned short* __restrict__ ctx, const unsigned short* __restrict__ WoT,
    const float* __restrict__ bo, float* __restrict__ out) {
  __shared__ __align__(16) unsigned short lds[2*(MT+NT)*KT];
  gemm_core<3>(lds, ctx, WoT, bo, out, 1.0f);
}

// ---------------- flash attention, software-pipelined ----------------
// grid: 1024 = (b,h) * 16 q-tiles of 64 rows; 4 waves x 16 q-rows each.
// K[kt+1] register-double-buffered (ping-pong via unroll-2, static indexing);
// V[kt] + gauss/mask issued at iteration top so latency hides under QK^T+softmax.
// Mask folded into gauss weight (p = 0 exactly for masked keys; normalization
// makes this equivalent to -inf masking).
__global__ __launch_bounds__(256) void attn(
    const unsigned short* __restrict__ Qp, const unsigned short* __restrict__ Kp,
    const unsigned short* __restrict__ VT, const int* __restrict__ mask,
    const float* __restrict__ gauss, unsigned short* __restrict__ ctx) {
  __shared__ __align__(16) unsigned short P[4][16][72];   // +8 pad: 2-way conflicts only
  int blk = blockIdx.x;
  int qt = blk & 15, bh = blk >> 4, b = bh >> 4, h = bh & 15;
  int tid = threadIdx.x, w = tid >> 6, l = tid & 63;
  int lr = l & 15, lg = l >> 4;
  int q0 = qt*64 + w*16;

  const unsigned short* Qb = Qp + (size_t)(b*SEQ + q0 + lr)*DIM + h*DH + lg*8;
  bf16x8 aq0 = *(const bf16x8*)Qb;
  bf16x8 aq1 = *(const bf16x8*)(Qb + 32);

  float m_[4], l_[4];
  f32x4 cacc[4] = {};
#pragma unroll
  for (int r = 0; r < 4; r++) { m_[r] = -1e30f; l_[r] = 0.f; }

  const int*   mrow = mask  + b*SEQ;
  const float* grow = gauss + b*SEQ;
  const unsigned short* Kb0 = Kp + (size_t)(b*SEQ + lr)*DIM + h*DH + lg*8;
  const unsigned short* Vb0 = VT + (size_t)((b*NH + h)*DH + lr)*SEQ + lg*8;

  bf16x8 kb0[4][2], kb1[4][2];
  // prologue: K tile 0
#pragma unroll
  for (int nf = 0; nf < 4; nf++) {
    kb0[nf][0] = *(const bf16x8*)(Kb0 + (size_t)(nf*16)*DIM);
    kb0[nf][1] = *(const bf16x8*)(Kb0 + (size_t)(nf*16)*DIM + 32);
  }

  auto body = [&](bf16x8 (&kc)[4][2], bf16x8 (&kn)[4][2], int kt) {
    int key0 = kt*64;
    int keyn = ((kt+1) & 15)*64;   // wraps at kt=15: harmless reload of tile 0
    // ---- issue next-K loads (consumed next iteration: ~full iter of latency cover) ----
#pragma unroll
    for (int nf = 0; nf < 4; nf++) {
      kn[nf][0] = *(const bf16x8*)(Kb0 + (size_t)(keyn + nf*16)*DIM);
      kn[nf][1] = *(const bf16x8*)(Kb0 + (size_t)(keyn + nf*16)*DIM + 32);
    }
    // ---- issue V loads for this tile (consumed after softmax, ~400cyc later) ----
    bf16x8 vf[4][2];
#pragma unroll
    for (int dt = 0; dt < 4; dt++) {
      vf[dt][0] = *(const bf16x8*)(Vb0 + (size_t)(dt*16)*SEQ + key0);
      vf[dt][1] = *(const bf16x8*)(Vb0 + (size_t)(dt*16)*SEQ + key0 + 32);
    }
    // ---- gauss * mask (issued early; mask folded: p==0 exactly for masked keys) ----
    float gwv[4];
#pragma unroll
    for (int nf = 0; nf < 4; nf++) {
      int key = key0 + nf*16 + lr;
      gwv[nf] = mrow[key] ? grow[key] + 1e-10f : 0.f;
    }
    // ---- S = Q K^T with current K regs (loaded one full iteration ago) ----
    f32x4 sa[4] = {};
    __builtin_amdgcn_s_setprio(1);
#pragma unroll
    for (int nf = 0; nf < 4; nf++) {
      sa[nf] = __builtin_amdgcn_mfma_f32_16x16x32_bf16(aq0, kc[nf][0], sa[nf], 0, 0, 0);
      sa[nf] = __builtin_amdgcn_mfma_f32_16x16x32_bf16(aq1, kc[nf][1], sa[nf], 0, 0, 0);
    }
    __builtin_amdgcn_s_setprio(0);
    // ---- online softmax (row = 16 lanes x 4 frags) ----
    float alpha[4];
#pragma unroll
    for (int r = 0; r < 4; r++) {
      float v = fmaxf(fmaxf(sa[0][r], sa[1][r]), fmaxf(sa[2][r], sa[3][r]));
      v = fmaxf(v, __shfl_xor(v, 1));
      v = fmaxf(v, __shfl_xor(v, 2));
      v = fmaxf(v, __shfl_xor(v, 4));
      v = fmaxf(v, __shfl_xor(v, 8));
      float mn = fmaxf(m_[r], v);
      alpha[r] = __expf(m_[r] - mn);
      m_[r] = mn;
    }
    float rsum[4] = {0.f, 0.f, 0.f, 0.f};
    unsigned short pb[4][4];
#pragma unroll
    for (int nf = 0; nf < 4; nf++)
#pragma unroll
      for (int r = 0; r < 4; r++) {
        float p = __expf(sa[nf][r] - m_[r]) * gwv[nf];
        pb[nf][r] = f2bf(p);
        rsum[r] += p;
      }
#pragma unroll
    for (int r = 0; r < 4; r++) {
      float v = rsum[r];
      v += __shfl_xor(v, 1);
      v += __shfl_xor(v, 2);
      v += __shfl_xor(v, 4);
      v += __shfl_xor(v, 8);
      l_[r] = l_[r]*alpha[r] + v;
    }
#pragma unroll
    for (int dt = 0; dt < 4; dt++)
#pragma unroll
      for (int r = 0; r < 4; r++) cacc[dt][r] *= alpha[r];
    // ---- transpose P (C-layout -> A-frag layout) through wave-local LDS ----
#pragma unroll
    for (int nf = 0; nf < 4; nf++)
#pragma unroll
      for (int r = 0; r < 4; r++)
        P[w][lg*4 + r][nf*16 + lr] = pb[nf][r];
    asm volatile("s_waitcnt lgkmcnt(0)" ::: "memory");
    __builtin_amdgcn_sched_barrier(0);
    bf16x8 ap0 = *(const bf16x8*)&P[w][lr][lg*8];
    bf16x8 ap1 = *(const bf16x8*)&P[w][lr][lg*8 + 32];
    // ---- context += P @ V (V already in regs, latency hidden) ----
    __builtin_amdgcn_s_setprio(1);
#pragma unroll
    for (int dt = 0; dt < 4; dt++) {
      cacc[dt] = __builtin_amdgcn_mfma_f32_16x16x32_bf16(ap0, vf[dt][0], cacc[dt], 0, 0, 0);
      cacc[dt] = __builtin_amdgcn_mfma_f32_16x16x32_bf16(ap1, vf[dt][1], cacc[dt], 0, 0, 0);
    }
    __builtin_amdgcn_s_setprio(0);
  };

  for (int kt = 0; kt < 16; kt += 2) {
    body(kb0, kb1, kt);
    body(kb1, kb0, kt + 1);
  }

  // ---- epilogue: normalize, write bf16 context (natural [b*s][dim]) ----
#pragma unroll
  for (int r = 0; r < 4; r++) {
    float inv = 1.0f / l_[r];
    int s = q0 + lg*4 + r;
#pragma unroll
    for (int dt = 0; dt < 4; dt++)
      ctx[(size_t)(b*SEQ + s)*DIM + h*DH + dt*16 + lr] = f2bf(cacc[dt][r] * inv);
  }
}

// ---------------- launch ----------------
extern "C" void kernel_launch(void* const* d_in, const int* in_sizes, int n_in,
                              void* d_out, int out_size, void* d_ws, size_t ws_size,
                              hipStream_t stream) {
  const float* query = (const float*)d_in[0];
  const float* key   = (const float*)d_in[1];
  const float* value = (const float*)d_in[2];
  const int*   mask  = (const int*)d_in[3];
  const float* gauss = (const float*)d_in[4];
  const float* Wq = (const float*)d_in[5];
  const float* bq = (const float*)d_in[6];
  const float* Wk = (const float*)d_in[7];
  const float* bk = (const float*)d_in[8];
  const float* Wv = (const float*)d_in[9];
  const float* bv = (const float*)d_in[10];
  const float* Wo = (const float*)d_in[11];
  const float* bo = (const float*)d_in[12];

  char* ws = (char*)d_ws;
  const size_t MB = 1024*1024;
  unsigned short* qb  = (unsigned short*)(ws + 0*MB);   // bf16 casts of inputs (8MB each)
  unsigned short* kb  = (unsigned short*)(ws + 8*MB);
  unsigned short* vb  = (unsigned short*)(ws + 16*MB);
  unsigned short* WqT = (unsigned short*)(ws + 24*MB);  // transposed bf16 weights (2MB each)
  unsigned short* WkT = (unsigned short*)(ws + 26*MB);
  unsigned short* WvT = (unsigned short*)(ws + 28*MB);
  unsigned short* WoT = (unsigned short*)(ws + 30*MB);
  unsigned short* Qp  = (unsigned short*)(ws + 32*MB);  // projected Q (scaled), natural layout
  unsigned short* Kp  = (unsigned short*)(ws + 40*MB);  // projected K, natural layout
  unsigned short* VTb = (unsigned short*)(ws + 48*MB);  // projected V, [b][h][d][s]
  unsigned short* ctx = (unsigned short*)(ws + 56*MB);  // attention output, natural layout

  cast_qkv<<<dim3((BS*SEQ*DIM)/(256*8), 3), 256, 0, stream>>>(query, key, value, qb, kb, vb);
  wcast_t<<<dim3(DIM/32, DIM/32, 4), 256, 0, stream>>>(Wq, Wk, Wv, Wo, WqT, WkT, WvT, WoT);
  qkv_gemm<<<dim3(NWG, 3), 256, 0, stream>>>(qb, kb, vb, WqT, WkT, WvT, bq, bk, bv, Qp, Kp, VTb);
  attn<<<BS*NH*(SEQ/64), 256, 0, stream>>>(Qp, Kp, VTb, mask, gauss, ctx);
  out_gemm<<<NWG, 256, 0, stream>>>(ctx, WoT, bo, (float*)d_out);
}

// Round 5
// 213.353 us; speedup vs baseline: 1.2695x; 1.2695x over previous
//
#include <hip/hip_runtime.h>
#include <stdint.h>

#define BS 4
#define SEQ 1024
#define DIM 1024
#define NH 16
#define DH 64
#define MROWS (BS*SEQ)   // 4096

#define MT 128
#define NT 64
#define KT 32
#define NBM (MROWS/MT)   // 32
#define NBN (DIM/NT)     // 16
#define NWG (NBM*NBN)    // 512
#define NKT (DIM/KT)     // 32

typedef __attribute__((ext_vector_type(8))) short bf16x8;
typedef __attribute__((ext_vector_type(4))) float f32x4;
typedef __attribute__((ext_vector_type(8))) unsigned short ushort8;
typedef __attribute__((ext_vector_type(4))) float float4v;

__device__ __forceinline__ unsigned short f2bf(float x) {
  union { float f; uint32_t u; } a; a.f = x;
  uint32_t r = (a.u + 0x7FFFu + ((a.u >> 16) & 1u)) >> 16;  // RNE
  return (unsigned short)r;
}

typedef const void __attribute__((address_space(1)))* gvp;
typedef void __attribute__((address_space(3)))* lvp;
__device__ __forceinline__ void gld_lds16(const void* g, void* l) {
  // async global->LDS, 16B/lane; LDS dest = wave-uniform base + lane*16
  __builtin_amdgcn_global_load_lds((gvp)g, (lvp)l, 16, 0, 0);
}

// ---------------- fp32 -> bf16 cast (query/key/value) ----------------
__global__ __launch_bounds__(256) void cast_qkv(
    const float* __restrict__ q, const float* __restrict__ k, const float* __restrict__ v,
    unsigned short* __restrict__ qo, unsigned short* __restrict__ ko, unsigned short* __restrict__ vo) {
  const float* s = blockIdx.y == 0 ? q : (blockIdx.y == 1 ? k : v);
  unsigned short* d = blockIdx.y == 0 ? qo : (blockIdx.y == 1 ? ko : vo);
  size_t i = ((size_t)blockIdx.x * 256 + threadIdx.x) * 8;
  float4v x0 = *(const float4v*)(s + i);
  float4v x1 = *(const float4v*)(s + i + 4);
  ushort8 r;
  r[0]=f2bf(x0[0]); r[1]=f2bf(x0[1]); r[2]=f2bf(x0[2]); r[3]=f2bf(x0[3]);
  r[4]=f2bf(x1[0]); r[5]=f2bf(x1[1]); r[6]=f2bf(x1[2]); r[7]=f2bf(x1[3]);
  *(ushort8*)(d + i) = r;
}

// ---------------- weight cast + transpose: WT[n][k] = bf16(W[k][n]) ----------------
__global__ __launch_bounds__(256) void wcast_t(
    const float* __restrict__ w0, const float* __restrict__ w1,
    const float* __restrict__ w2, const float* __restrict__ w3,
    unsigned short* __restrict__ t0, unsigned short* __restrict__ t1,
    unsigned short* __restrict__ t2, unsigned short* __restrict__ t3) {
  __shared__ float tile[32][33];
  const float* W = blockIdx.z == 0 ? w0 : blockIdx.z == 1 ? w1 : blockIdx.z == 2 ? w2 : w3;
  unsigned short* T = blockIdx.z == 0 ? t0 : blockIdx.z == 1 ? t1 : blockIdx.z == 2 ? t2 : t3;
  int tx = threadIdx.x & 31, ty = threadIdx.x >> 5;   // 32 x 8
  int bx = blockIdx.x, by = blockIdx.y;
#pragma unroll
  for (int j = 0; j < 4; j++)
    tile[ty + 8*j][tx] = W[(size_t)(by*32 + ty + 8*j)*DIM + bx*32 + tx];
  __syncthreads();
#pragma unroll
  for (int j = 0; j < 4; j++)
    T[(size_t)(bx*32 + ty + 8*j)*DIM + by*32 + tx] = f2bf(tile[tx][ty + 8*j]);
}

// ---------------- GEMM core: C[M=4096,N=1024] = A @ BT^T (+bias) ----------------
// MODE 0: bf16 out, (acc+bias)*scale, natural [row][col]
// MODE 2: bf16 out, acc+bias, written transposed per head: VT[b][h][d][s]
// MODE 3: f32 out, acc+bias
template<int MODE>
__device__ __forceinline__ void gemm_core(
    unsigned short* lds,
    const unsigned short* __restrict__ A, const unsigned short* __restrict__ BT,
    const float* __restrict__ bias, void* __restrict__ outp, float scale) {
  unsigned short* Abase = lds;                 // 2 x MT*KT
  unsigned short* Bbase = lds + 2*MT*KT;       // 2 x NT*KT
  int id = blockIdx.x;
  int sw = (id & 7) * (NWG/8) + (id >> 3);     // XCD-aware swizzle (bijective, 512%8==0)
  int bm = sw & (NBM-1), bn = sw >> 5;
  int tid = threadIdx.x, w = tid >> 6, l = tid & 63;
  int wr = w >> 1, wc = w & 1;
  int lr = l & 15, lg = l >> 4;

  auto stage = [&](int buf, int kt) {
    const unsigned short* a0 = A + (size_t)(bm*MT + w*32 + (l>>2))*DIM + kt*KT + (l&3)*8;
    gld_lds16(a0,          Abase + buf*MT*KT + (w*32)*KT);
    gld_lds16(a0 + 16*DIM, Abase + buf*MT*KT + (w*32 + 16)*KT);
    const unsigned short* b0 = BT + (size_t)(bn*NT + w*16 + (l>>2))*DIM + kt*KT + (l&3)*8;
    gld_lds16(b0,          Bbase + buf*NT*KT + (w*16)*KT);
  };

  f32x4 acc[4][2] = {};
  int buf = 0;
  stage(0, 0);
  __syncthreads();
  for (int kt = 0; kt < NKT; kt++) {
    if (kt + 1 < NKT) stage(buf ^ 1, kt + 1);
    unsigned short* As = Abase + buf*MT*KT;
    unsigned short* Bs = Bbase + buf*NT*KT;
    bf16x8 af[4], bf_[2];
#pragma unroll
    for (int mi = 0; mi < 4; mi++)
      af[mi] = *(const bf16x8*)&As[(wr*64 + mi*16 + lr)*KT + lg*8];
#pragma unroll
    for (int ni = 0; ni < 2; ni++)
      bf_[ni] = *(const bf16x8*)&Bs[(wc*32 + ni*16 + lr)*KT + lg*8];
#pragma unroll
    for (int mi = 0; mi < 4; mi++)
#pragma unroll
      for (int ni = 0; ni < 2; ni++)
        acc[mi][ni] = __builtin_amdgcn_mfma_f32_16x16x32_bf16(af[mi], bf_[ni], acc[mi][ni], 0, 0, 0);
    __syncthreads();   // drains vmcnt for the staged next tile + protects buffer reuse
    buf ^= 1;
  }

  int row0 = bm*MT + wr*64;
  int col0 = bn*NT + wc*32;
#pragma unroll
  for (int ni = 0; ni < 2; ni++) {
    int col = col0 + ni*16 + lr;
    float bv = bias[col];
#pragma unroll
    for (int mi = 0; mi < 4; mi++)
#pragma unroll
      for (int r = 0; r < 4; r++) {
        int row = row0 + mi*16 + lg*4 + r;
        float val = acc[mi][ni][r] + bv;
        if (MODE == 0) {
          ((unsigned short*)outp)[(size_t)row*DIM + col] = f2bf(val * scale);
        } else if (MODE == 2) {
          int b = row >> 10, s = row & 1023, h = col >> 6, d = col & 63;
          ((unsigned short*)outp)[(size_t)((b*NH + h)*DH + d)*SEQ + s] = f2bf(val);
        } else {
          ((float*)outp)[(size_t)row*DIM + col] = val;
        }
      }
  }
}

__global__ __launch_bounds__(256) void qkv_gemm(
    const unsigned short* __restrict__ qb, const unsigned short* __restrict__ kb,
    const unsigned short* __restrict__ vb,
    const unsigned short* __restrict__ WqT, const unsigned short* __restrict__ WkT,
    const unsigned short* __restrict__ WvT,
    const float* __restrict__ bq, const float* __restrict__ bk, const float* __restrict__ bv,
    unsigned short* __restrict__ Qp, unsigned short* __restrict__ Kp,
    unsigned short* __restrict__ VT) {
  __shared__ __align__(16) unsigned short lds[2*(MT+NT)*KT];
  int z = blockIdx.y;
  if (z == 0)      gemm_core<0>(lds, qb, WqT, bq, Qp, 0.125f);   // 1/sqrt(64)
  else if (z == 1) gemm_core<0>(lds, kb, WkT, bk, Kp, 1.0f);
  else             gemm_core<2>(lds, vb, WvT, bv, VT, 1.0f);
}

__global__ __launch_bounds__(256) void out_gemm(
    const unsigned short* __restrict__ ctx, const unsigned short* __restrict__ WoT,
    const float* __restrict__ bo, float* __restrict__ out) {
  __shared__ __align__(16) unsigned short lds[2*(MT+NT)*KT];
  gemm_core<3>(lds, ctx, WoT, bo, out, 1.0f);
}

// ---------------- flash attention: K double-buffered in LDS via global_load_lds ----------------
// grid: 1024 = (b,h) * 16 q-tiles of 64 rows; 4 waves x 16 q-rows each.
// All 4 waves share the K tile -> LDS staging removes 4x redundant loads AND
// gives a full iteration of latency cover with ZERO register cost (the R4
// register-prefetch failure mode). K tile is XOR-swizzled (slot ^= row&7) via
// pre-swizzled global source + swizzled ds_read (both-sides rule): b128 reads
// land 8 lanes / 16B bank-group = LDS floor. V loaded to regs after QK^T,
// consumed after softmax (~300cyc VALU cover). Mask folded into gauss weight.
__global__ __launch_bounds__(256) void attn(
    const unsigned short* __restrict__ Qp, const unsigned short* __restrict__ Kp,
    const unsigned short* __restrict__ VT, const int* __restrict__ mask,
    const float* __restrict__ gauss, unsigned short* __restrict__ ctx) {
  __shared__ __align__(16) unsigned short Klds[2*64*64];  // 16KB double-buffered K tile
  __shared__ __align__(16) unsigned short P[4][16][72];   // +8 pad: uniform slot spread on b128
  int blk = blockIdx.x;
  int qt = blk & 15, bh = blk >> 4, b = bh >> 4, h = bh & 15;
  int tid = threadIdx.x, w = tid >> 6, l = tid & 63;
  int lr = l & 15, lg = l >> 4;
  int q0 = qt*64 + w*16;

  const unsigned short* Qb = Qp + (size_t)(b*SEQ + q0 + lr)*DIM + h*DH + lg*8;
  bf16x8 aq0 = *(const bf16x8*)Qb;
  bf16x8 aq1 = *(const bf16x8*)(Qb + 32);

  float m_[4], l_[4];
  f32x4 cacc[4] = {};
#pragma unroll
  for (int r = 0; r < 4; r++) { m_[r] = -1e30f; l_[r] = 0.f; }

  const int*   mrow = mask  + b*SEQ;
  const float* grow = gauss + b*SEQ;
  const unsigned short* Krow0 = Kp + (size_t)(b*SEQ)*DIM + h*DH;       // + s*DIM per key
  const unsigned short* Vb0   = VT + (size_t)((b*NH + h)*DH + lr)*SEQ + lg*8;

  // staging geometry: each wave stages rows w*16..w*16+15 (2 instrs of 8 rows).
  // lane l covers row (l>>3), 16B slot (l&7); source slot pre-swizzled by row&7.
  int srow = l >> 3;                       // 0..7, == row&7 within each 8-row group
  int scol = ((l & 7) ^ srow) * 8;         // element offset of pre-swizzled 16B slot
  auto stageK = [&](int buf, int key0) {
    gld_lds16(Krow0 + (size_t)(key0 + w*16 +     srow)*DIM + scol, Klds + buf*64*64 + (w*16    )*64);
    gld_lds16(Krow0 + (size_t)(key0 + w*16 + 8 + srow)*DIM + scol, Klds + buf*64*64 + (w*16 + 8)*64);
  };

  stageK(0, 0);
  __syncthreads();
  int buf = 0;
  for (int kt = 0; kt < 16; kt++) {
    int key0 = kt*64;
    // ---- issue next-K tile stage (async, zero VGPR, drained by end-of-iter barrier) ----
    if (kt < 15) stageK(buf ^ 1, key0 + 64);
    // ---- gauss * mask (issued early, consumed in softmax) ----
    float gwv[4];
#pragma unroll
    for (int nf = 0; nf < 4; nf++) {
      int key = key0 + nf*16 + lr;
      gwv[nf] = mrow[key] ? grow[key] + 1e-10f : 0.f;
    }
    // ---- S = Q K^T from LDS (swizzled read) ----
    const unsigned short* Kt = Klds + buf*64*64;
    f32x4 sa[4] = {};
#pragma unroll
    for (int nf = 0; nf < 4; nf++) {
      int r1 = nf*16 + lr;
      int rx = r1 & 7;
      bf16x8 k0 = *(const bf16x8*)&Kt[r1*64 + ((lg       ^ rx) * 8)];
      bf16x8 k1 = *(const bf16x8*)&Kt[r1*64 + (((lg + 4) ^ rx) * 8)];
      sa[nf] = __builtin_amdgcn_mfma_f32_16x16x32_bf16(aq0, k0, sa[nf], 0, 0, 0);
      sa[nf] = __builtin_amdgcn_mfma_f32_16x16x32_bf16(aq1, k1, sa[nf], 0, 0, 0);
    }
    // ---- issue V loads now; softmax below covers their latency ----
    bf16x8 vf[4][2];
#pragma unroll
    for (int dt = 0; dt < 4; dt++) {
      vf[dt][0] = *(const bf16x8*)(Vb0 + (size_t)(dt*16)*SEQ + key0);
      vf[dt][1] = *(const bf16x8*)(Vb0 + (size_t)(dt*16)*SEQ + key0 + 32);
    }
    // ---- online softmax (row = 16 lanes x 4 frags) ----
    float alpha[4];
#pragma unroll
    for (int r = 0; r < 4; r++) {
      float v = fmaxf(fmaxf(sa[0][r], sa[1][r]), fmaxf(sa[2][r], sa[3][r]));
      v = fmaxf(v, __shfl_xor(v, 1));
      v = fmaxf(v, __shfl_xor(v, 2));
      v = fmaxf(v, __shfl_xor(v, 4));
      v = fmaxf(v, __shfl_xor(v, 8));
      float mn = fmaxf(m_[r], v);
      alpha[r] = __expf(m_[r] - mn);
      m_[r] = mn;
    }
    float rsum[4] = {0.f, 0.f, 0.f, 0.f};
    unsigned short pb[4][4];
#pragma unroll
    for (int nf = 0; nf < 4; nf++)
#pragma unroll
      for (int r = 0; r < 4; r++) {
        float p = __expf(sa[nf][r] - m_[r]) * gwv[nf];
        pb[nf][r] = f2bf(p);
        rsum[r] += p;
      }
#pragma unroll
    for (int r = 0; r < 4; r++) {
      float v = rsum[r];
      v += __shfl_xor(v, 1);
      v += __shfl_xor(v, 2);
      v += __shfl_xor(v, 4);
      v += __shfl_xor(v, 8);
      l_[r] = l_[r]*alpha[r] + v;
    }
#pragma unroll
    for (int dt = 0; dt < 4; dt++)
#pragma unroll
      for (int r = 0; r < 4; r++) cacc[dt][r] *= alpha[r];
    // ---- transpose P (C-layout -> A-frag layout) through wave-local LDS ----
#pragma unroll
    for (int nf = 0; nf < 4; nf++)
#pragma unroll
      for (int r = 0; r < 4; r++)
        P[w][lg*4 + r][nf*16 + lr] = pb[nf][r];
    asm volatile("s_waitcnt lgkmcnt(0)" ::: "memory");
    __builtin_amdgcn_sched_barrier(0);
    bf16x8 ap0 = *(const bf16x8*)&P[w][lr][lg*8];
    bf16x8 ap1 = *(const bf16x8*)&P[w][lr][lg*8 + 32];
    // ---- context += P @ V (V latency hidden under softmax) ----
#pragma unroll
    for (int dt = 0; dt < 4; dt++) {
      cacc[dt] = __builtin_amdgcn_mfma_f32_16x16x32_bf16(ap0, vf[dt][0], cacc[dt], 0, 0, 0);
      cacc[dt] = __builtin_amdgcn_mfma_f32_16x16x32_bf16(ap1, vf[dt][1], cacc[dt], 0, 0, 0);
    }
    __syncthreads();   // drains staged next-K (vmcnt 0) + protects K buffer reuse
    buf ^= 1;
  }

  // ---- epilogue: normalize, write bf16 context (natural [b*s][dim]) ----
#pragma unroll
  for (int r = 0; r < 4; r++) {
    float inv = 1.0f / l_[r];
    int s = q0 + lg*4 + r;
#pragma unroll
    for (int dt = 0; dt < 4; dt++)
      ctx[(size_t)(b*SEQ + s)*DIM + h*DH + dt*16 + lr] = f2bf(cacc[dt][r] * inv);
  }
}

// ---------------- launch ----------------
extern "C" void kernel_launch(void* const* d_in, const int* in_sizes, int n_in,
                              void* d_out, int out_size, void* d_ws, size_t ws_size,
                              hipStream_t stream) {
  const float* query = (const float*)d_in[0];
  const float* key   = (const float*)d_in[1];
  const float* value = (const float*)d_in[2];
  const int*   mask  = (const int*)d_in[3];
  const float* gauss = (const float*)d_in[4];
  const float* Wq = (const float*)d_in[5];
  const float* bq = (const float*)d_in[6];
  const float* Wk = (const float*)d_in[7];
  const float* bk = (const float*)d_in[8];
  const float* Wv = (const float*)d_in[9];
  const float* bv = (const float*)d_in[10];
  const float* Wo = (const float*)d_in[11];
  const float* bo = (const float*)d_in[12];

  char* ws = (char*)d_ws;
  const size_t MB = 1024*1024;
  unsigned short* qb  = (unsigned short*)(ws + 0*MB);   // bf16 casts of inputs (8MB each)
  unsigned short* kb  = (unsigned short*)(ws + 8*MB);
  unsigned short* vb  = (unsigned short*)(ws + 16*MB);
  unsigned short* WqT = (unsigned short*)(ws + 24*MB);  // transposed bf16 weights (2MB each)
  unsigned short* WkT = (unsigned short*)(ws + 26*MB);
  unsigned short* WvT = (unsigned short*)(ws + 28*MB);
  unsigned short* WoT = (unsigned short*)(ws + 30*MB);
  unsigned short* Qp  = (unsigned short*)(ws + 32*MB);  // projected Q (scaled), natural layout
  unsigned short* Kp  = (unsigned short*)(ws + 40*MB);  // projected K, natural layout
  unsigned short* VTb = (unsigned short*)(ws + 48*MB);  // projected V, [b][h][d][s]
  unsigned short* ctx = (unsigned short*)(ws + 56*MB);  // attention output, natural layout

  cast_qkv<<<dim3((BS*SEQ*DIM)/(256*8), 3), 256, 0, stream>>>(query, key, value, qb, kb, vb);
  wcast_t<<<dim3(DIM/32, DIM/32, 4), 256, 0, stream>>>(Wq, Wk, Wv, Wo, WqT, WkT, WvT, WoT);
  qkv_gemm<<<dim3(NWG, 3), 256, 0, stream>>>(qb, kb, vb, WqT, WkT, WvT, bq, bk, bv, Qp, Kp, VTb);
  attn<<<BS*NH*(SEQ/64), 256, 0, stream>>>(Qp, Kp, VTb, mask, gauss, ctx);
  out_gemm<<<NWG, 256, 0, stream>>>(ctx, WoT, bo, (float*)d_out);
}

// Round 6
// 153.569 us; speedup vs baseline: 1.7637x; 1.3893x over previous
//
#include <hip/hip_runtime.h>
#include <stdint.h>

#define BS 4
#define SEQ 1024
#define DIM 1024
#define NH 16
#define DH 64
#define MROWS (BS*SEQ)   // 4096

#define MT 128
#define NT 64
#define KT 32
#define NBM (MROWS/MT)   // 32
#define NBN (DIM/NT)     // 16
#define NWG (NBM*NBN)    // 512
#define NKT (DIM/KT)     // 32

typedef __attribute__((ext_vector_type(8))) short bf16x8;
typedef __attribute__((ext_vector_type(4))) float f32x4;
typedef __attribute__((ext_vector_type(8))) unsigned short ushort8;
typedef __attribute__((ext_vector_type(4))) float float4v;
typedef __attribute__((ext_vector_type(4))) int int4v;
typedef __attribute__((ext_vector_type(2))) unsigned int uint32x2;

__device__ __forceinline__ unsigned short f2bf(float x) {
  union { float f; uint32_t u; } a; a.f = x;
  uint32_t r = (a.u + 0x7FFFu + ((a.u >> 16) & 1u)) >> 16;  // RNE
  return (unsigned short)r;
}

// packed f32x2 -> bf16x2 (lo = first arg); no builtin on gfx950 -> inline asm (T12)
__device__ __forceinline__ uint32_t cvtpk_bf16(float lo, float hi) {
  uint32_t d;
  asm("v_cvt_pk_bf16_f32 %0, %1, %2" : "=v"(d) : "v"(lo), "v"(hi));
  return d;
}

typedef const void __attribute__((address_space(1)))* gvp;
typedef void __attribute__((address_space(3)))* lvp;
__device__ __forceinline__ void gld_lds16(const void* g, void* l) {
  // async global->LDS, 16B/lane; LDS dest = wave-uniform base + lane*16
  __builtin_amdgcn_global_load_lds((gvp)g, (lvp)l, 16, 0, 0);
}

// ---------------- fp32 -> bf16 cast (query/key/value) ----------------
__global__ __launch_bounds__(256) void cast_qkv(
    const float* __restrict__ q, const float* __restrict__ k, const float* __restrict__ v,
    unsigned short* __restrict__ qo, unsigned short* __restrict__ ko, unsigned short* __restrict__ vo) {
  const float* s = blockIdx.y == 0 ? q : (blockIdx.y == 1 ? k : v);
  unsigned short* d = blockIdx.y == 0 ? qo : (blockIdx.y == 1 ? ko : vo);
  size_t i = ((size_t)blockIdx.x * 256 + threadIdx.x) * 8;
  float4v x0 = *(const float4v*)(s + i);
  float4v x1 = *(const float4v*)(s + i + 4);
  ushort8 r;
  r[0]=f2bf(x0[0]); r[1]=f2bf(x0[1]); r[2]=f2bf(x0[2]); r[3]=f2bf(x0[3]);
  r[4]=f2bf(x1[0]); r[5]=f2bf(x1[1]); r[6]=f2bf(x1[2]); r[7]=f2bf(x1[3]);
  *(ushort8*)(d + i) = r;
}

// ---------------- weight cast + transpose: WT[n][k] = bf16(W[k][n]) ----------------
__global__ __launch_bounds__(256) void wcast_t(
    const float* __restrict__ w0, const float* __restrict__ w1,
    const float* __restrict__ w2, const float* __restrict__ w3,
    unsigned short* __restrict__ t0, unsigned short* __restrict__ t1,
    unsigned short* __restrict__ t2, unsigned short* __restrict__ t3) {
  __shared__ float tile[32][33];
  const float* W = blockIdx.z == 0 ? w0 : blockIdx.z == 1 ? w1 : blockIdx.z == 2 ? w2 : w3;
  unsigned short* T = blockIdx.z == 0 ? t0 : blockIdx.z == 1 ? t1 : blockIdx.z == 2 ? t2 : t3;
  int tx = threadIdx.x & 31, ty = threadIdx.x >> 5;   // 32 x 8
  int bx = blockIdx.x, by = blockIdx.y;
#pragma unroll
  for (int j = 0; j < 4; j++)
    tile[ty + 8*j][tx] = W[(size_t)(by*32 + ty + 8*j)*DIM + bx*32 + tx];
  __syncthreads();
#pragma unroll
  for (int j = 0; j < 4; j++)
    T[(size_t)(bx*32 + ty + 8*j)*DIM + by*32 + tx] = f2bf(tile[tx][ty + 8*j]);
}

// ---------------- GEMM core: C[M=4096,N=1024] = A @ BT^T (+bias) ----------------
// MODE 0: bf16 out, (acc+bias)*scale, natural [row][col]
// MODE 2: bf16 out, acc+bias, written transposed per head: VT[b][h][d][s]
// MODE 3: f32 out, acc+bias
template<int MODE>
__device__ __forceinline__ void gemm_core(
    unsigned short* lds,
    const unsigned short* __restrict__ A, const unsigned short* __restrict__ BT,
    const float* __restrict__ bias, void* __restrict__ outp, float scale) {
  unsigned short* Abase = lds;                 // 2 x MT*KT
  unsigned short* Bbase = lds + 2*MT*KT;       // 2 x NT*KT
  int id = blockIdx.x;
  int sw = (id & 7) * (NWG/8) + (id >> 3);     // XCD-aware swizzle (bijective, 512%8==0)
  int bm = sw & (NBM-1), bn = sw >> 5;
  int tid = threadIdx.x, w = tid >> 6, l = tid & 63;
  int wr = w >> 1, wc = w & 1;
  int lr = l & 15, lg = l >> 4;

  auto stage = [&](int buf, int kt) {
    const unsigned short* a0 = A + (size_t)(bm*MT + w*32 + (l>>2))*DIM + kt*KT + (l&3)*8;
    gld_lds16(a0,          Abase + buf*MT*KT + (w*32)*KT);
    gld_lds16(a0 + 16*DIM, Abase + buf*MT*KT + (w*32 + 16)*KT);
    const unsigned short* b0 = BT + (size_t)(bn*NT + w*16 + (l>>2))*DIM + kt*KT + (l&3)*8;
    gld_lds16(b0,          Bbase + buf*NT*KT + (w*16)*KT);
  };

  f32x4 acc[4][2] = {};
  int buf = 0;
  stage(0, 0);
  __syncthreads();
  for (int kt = 0; kt < NKT; kt++) {
    if (kt + 1 < NKT) stage(buf ^ 1, kt + 1);
    unsigned short* As = Abase + buf*MT*KT;
    unsigned short* Bs = Bbase + buf*NT*KT;
    bf16x8 af[4], bf_[2];
#pragma unroll
    for (int mi = 0; mi < 4; mi++)
      af[mi] = *(const bf16x8*)&As[(wr*64 + mi*16 + lr)*KT + lg*8];
#pragma unroll
    for (int ni = 0; ni < 2; ni++)
      bf_[ni] = *(const bf16x8*)&Bs[(wc*32 + ni*16 + lr)*KT + lg*8];
#pragma unroll
    for (int mi = 0; mi < 4; mi++)
#pragma unroll
      for (int ni = 0; ni < 2; ni++)
        acc[mi][ni] = __builtin_amdgcn_mfma_f32_16x16x32_bf16(af[mi], bf_[ni], acc[mi][ni], 0, 0, 0);
    __syncthreads();   // drains vmcnt for the staged next tile + protects buffer reuse
    buf ^= 1;
  }

  int row0 = bm*MT + wr*64;
  int col0 = bn*NT + wc*32;
#pragma unroll
  for (int ni = 0; ni < 2; ni++) {
    int col = col0 + ni*16 + lr;
    float bv = bias[col];
#pragma unroll
    for (int mi = 0; mi < 4; mi++)
#pragma unroll
      for (int r = 0; r < 4; r++) {
        int row = row0 + mi*16 + lg*4 + r;
        float val = acc[mi][ni][r] + bv;
        if (MODE == 0) {
          ((unsigned short*)outp)[(size_t)row*DIM + col] = f2bf(val * scale);
        } else if (MODE == 2) {
          int b = row >> 10, s = row & 1023, h = col >> 6, d = col & 63;
          ((unsigned short*)outp)[(size_t)((b*NH + h)*DH + d)*SEQ + s] = f2bf(val);
        } else {
          ((float*)outp)[(size_t)row*DIM + col] = val;
        }
      }
  }
}

__global__ __launch_bounds__(256) void qkv_gemm(
    const unsigned short* __restrict__ qb, const unsigned short* __restrict__ kb,
    const unsigned short* __restrict__ vb,
    const unsigned short* __restrict__ WqT, const unsigned short* __restrict__ WkT,
    const unsigned short* __restrict__ WvT,
    const float* __restrict__ bq, const float* __restrict__ bk, const float* __restrict__ bv,
    unsigned short* __restrict__ Qp, unsigned short* __restrict__ Kp,
    unsigned short* __restrict__ VT) {
  __shared__ __align__(16) unsigned short lds[2*(MT+NT)*KT];
  int z = blockIdx.y;
  if (z == 0)      gemm_core<0>(lds, qb, WqT, bq, Qp, 0.125f);   // 1/sqrt(64)
  else if (z == 1) gemm_core<0>(lds, kb, WkT, bk, Kp, 1.0f);
  else             gemm_core<2>(lds, vb, WvT, bv, VT, 1.0f);
}

__global__ __launch_bounds__(256) void out_gemm(
    const unsigned short* __restrict__ ctx, const unsigned short* __restrict__ WoT,
    const float* __restrict__ bo, float* __restrict__ out) {
  __shared__ __align__(16) unsigned short lds[2*(MT+NT)*KT];
  gemm_core<3>(lds, ctx, WoT, bo, out, 1.0f);
}

// ---------------- flash attention, swapped-QK^T (lane owns one q-row) ----------------
// grid 1024; decode head-major (bh = blk&63) so all 16 q-tiles of a head land on
// one XCD (K+V 2MB/XCD fits L2). 4 waves x 16 q-rows. K LDS-staged (async dbuf,
// XOR-swizzled). S^T = mfma(K,Q): lane's 16 values all belong to q = lane&15 ->
// softmax state is per-lane scalar; max/sum reduce = 2 shfl each. P packed with
// v_cvt_pk_bf16_f32, written as 4x ds_write_b64, re-read as PV B-frag.
// PV: O^T = mfma(V^T, P). launch_bounds(256,4): 128-VGPR budget so the early
// V-prefetch stays live (R4/R5 failure: compiler sank loads at 64-VGPR target).
__global__ __launch_bounds__(256, 4) void attn(
    const unsigned short* __restrict__ Qp, const unsigned short* __restrict__ Kp,
    const unsigned short* __restrict__ VT, const int* __restrict__ mask,
    const float* __restrict__ gauss, unsigned short* __restrict__ ctx) {
  __shared__ __align__(16) unsigned short Klds[2*64*64];  // 16KB double-buffered K tile
  __shared__ __align__(16) unsigned short P[4][16][72];   // pad->2-way write, 8-way read (ok)
  __shared__ float gwl[SEQ];                              // mask-folded gauss weights
  int blk = blockIdx.x;
  int bh = blk & 63, qt = blk >> 6;        // head-major: head bh pinned to XCD bh%8
  int b = bh >> 4, h = bh & 15;
  int tid = threadIdx.x, w = tid >> 6, l = tid & 63;
  int lr = l & 15, lg = l >> 4;
  int q0 = qt*64 + w*16;

  // ---- stash mask-folded gauss row in LDS (once) ----
  {
    int i4 = tid * 4;
    float4v g4 = *(const float4v*)(gauss + b*SEQ + i4);
    int4v   m4 = *(const int4v*)(mask + b*SEQ + i4);
#pragma unroll
    for (int j = 0; j < 4; j++) gwl[i4 + j] = m4[j] ? g4[j] + 1e-10f : 0.f;
  }

  const unsigned short* Qb = Qp + (size_t)(b*SEQ + q0 + lr)*DIM + h*DH + lg*8;
  bf16x8 aq0 = *(const bf16x8*)Qb;
  bf16x8 aq1 = *(const bf16x8*)(Qb + 32);

  float m_ = -1e30f, l_ = 0.f;             // per-lane scalars (q = lr)
  f32x4 cacc[4] = {};                      // O^T[d = dt*16+lg*4+r][q = lr]

  const unsigned short* Krow0 = Kp + (size_t)(b*SEQ)*DIM + h*DH;
  const unsigned short* Vb0   = VT + (size_t)((b*NH + h)*DH + lr)*SEQ + lg*8;

  // staging geometry: lane l covers row (l>>3), 16B slot (l&7); source pre-swizzled by row&7
  int srow = l >> 3;
  int scol = ((l & 7) ^ srow) * 8;
  auto stageK = [&](int buf, int key0) {
    gld_lds16(Krow0 + (size_t)(key0 + w*16 +     srow)*DIM + scol, Klds + buf*64*64 + (w*16    )*64);
    gld_lds16(Krow0 + (size_t)(key0 + w*16 + 8 + srow)*DIM + scol, Klds + buf*64*64 + (w*16 + 8)*64);
  };

  stageK(0, 0);
  __syncthreads();
  int buf = 0;
  for (int kt = 0; kt < 16; kt++) {
    int key0 = kt*64;
    // ---- issue next-K stage (async, zero VGPR) ----
    if (kt < 15) stageK(buf ^ 1, key0 + 64);
    // ---- issue V loads early (consumed after softmax; 128-VGPR budget keeps them live) ----
    bf16x8 vf[4][2];
#pragma unroll
    for (int dt = 0; dt < 4; dt++) {
      vf[dt][0] = *(const bf16x8*)(Vb0 + (size_t)(dt*16)*SEQ + key0);
      vf[dt][1] = *(const bf16x8*)(Vb0 + (size_t)(dt*16)*SEQ + key0 + 32);
    }
    // ---- S^T = mfma(K, Q): sa[nf][r] = S[q=lr][key = nf*16 + lg*4 + r] ----
    const unsigned short* Kt = Klds + buf*64*64;
    f32x4 sa[4] = {};
#pragma unroll
    for (int nf = 0; nf < 4; nf++) {
      int r1 = nf*16 + lr;
      int rx = r1 & 7;
      bf16x8 k0 = *(const bf16x8*)&Kt[r1*64 + ((lg       ^ rx) * 8)];
      bf16x8 k1 = *(const bf16x8*)&Kt[r1*64 + (((lg + 4) ^ rx) * 8)];
      sa[nf] = __builtin_amdgcn_mfma_f32_16x16x32_bf16(k0, aq0, sa[nf], 0, 0, 0);
      sa[nf] = __builtin_amdgcn_mfma_f32_16x16x32_bf16(k1, aq1, sa[nf], 0, 0, 0);
    }
    // ---- online softmax, per-lane scalar state ----
    float mx = sa[0][0];
#pragma unroll
    for (int nf = 0; nf < 4; nf++)
#pragma unroll
      for (int r = 0; r < 4; r++) mx = fmaxf(mx, sa[nf][r]);
    mx = fmaxf(mx, __shfl_xor(mx, 16));
    mx = fmaxf(mx, __shfl_xor(mx, 32));
    float mn = fmaxf(m_, mx);
    float alpha = __expf(m_ - mn);
    m_ = mn;
    float rs = 0.f;
    uint32_t u[4][2];
#pragma unroll
    for (int nf = 0; nf < 4; nf++) {
      float4v g = *(const float4v*)&gwl[key0 + nf*16 + lg*4];   // broadcast LDS read
      float p0 = __expf(sa[nf][0] - m_) * g[0];
      float p1 = __expf(sa[nf][1] - m_) * g[1];
      float p2 = __expf(sa[nf][2] - m_) * g[2];
      float p3 = __expf(sa[nf][3] - m_) * g[3];
      rs += (p0 + p1) + (p2 + p3);
      u[nf][0] = cvtpk_bf16(p0, p1);
      u[nf][1] = cvtpk_bf16(p2, p3);
    }
    rs += __shfl_xor(rs, 16);
    rs += __shfl_xor(rs, 32);
    l_ = l_*alpha + rs;
#pragma unroll
    for (int dt = 0; dt < 4; dt++)
#pragma unroll
      for (int r = 0; r < 4; r++) cacc[dt][r] *= alpha;
    // ---- P[q=lr][key]: 4x ds_write_b64 (keys lg*4..+3 per nf) ----
#pragma unroll
    for (int nf = 0; nf < 4; nf++) {
      uint32x2 uu; uu[0] = u[nf][0]; uu[1] = u[nf][1];
      *(uint32x2*)&P[w][lr][nf*16 + lg*4] = uu;
    }
    asm volatile("s_waitcnt lgkmcnt(0)" ::: "memory");
    __builtin_amdgcn_sched_barrier(0);
    bf16x8 ap0 = *(const bf16x8*)&P[w][lr][lg*8];        // B-frag: keys 0..31
    bf16x8 ap1 = *(const bf16x8*)&P[w][lr][32 + lg*8];   // B-frag: keys 32..63
    // ---- O^T += mfma(V^T, P) ----
#pragma unroll
    for (int dt = 0; dt < 4; dt++) {
      cacc[dt] = __builtin_amdgcn_mfma_f32_16x16x32_bf16(vf[dt][0], ap0, cacc[dt], 0, 0, 0);
      cacc[dt] = __builtin_amdgcn_mfma_f32_16x16x32_bf16(vf[dt][1], ap1, cacc[dt], 0, 0, 0);
    }
    __syncthreads();   // drains staged next-K + protects K buffer reuse
    buf ^= 1;
  }

  // ---- epilogue: normalize, pack pairs, 4x b64 stores per lane ----
  float inv = 1.0f / l_;
  size_t row = (size_t)(b*SEQ + q0 + lr)*DIM + h*DH;
#pragma unroll
  for (int dt = 0; dt < 4; dt++) {
    uint32x2 e;
    e[0] = cvtpk_bf16(cacc[dt][0]*inv, cacc[dt][1]*inv);
    e[1] = cvtpk_bf16(cacc[dt][2]*inv, cacc[dt][3]*inv);
    *(uint32x2*)&ctx[row + dt*16 + lg*4] = e;
  }
}

// ---------------- launch ----------------
extern "C" void kernel_launch(void* const* d_in, const int* in_sizes, int n_in,
                              void* d_out, int out_size, void* d_ws, size_t ws_size,
                              hipStream_t stream) {
  const float* query = (const float*)d_in[0];
  const float* key   = (const float*)d_in[1];
  const float* value = (const float*)d_in[2];
  const int*   mask  = (const int*)d_in[3];
  const float* gauss = (const float*)d_in[4];
  const float* Wq = (const float*)d_in[5];
  const float* bq = (const float*)d_in[6];
  const float* Wk = (const float*)d_in[7];
  const float* bk = (const float*)d_in[8];
  const float* Wv = (const float*)d_in[9];
  const float* bv = (const float*)d_in[10];
  const float* Wo = (const float*)d_in[11];
  const float* bo = (const float*)d_in[12];

  char* ws = (char*)d_ws;
  const size_t MB = 1024*1024;
  unsigned short* qb  = (unsigned short*)(ws + 0*MB);   // bf16 casts of inputs (8MB each)
  unsigned short* kb  = (unsigned short*)(ws + 8*MB);
  unsigned short* vb  = (unsigned short*)(ws + 16*MB);
  unsigned short* WqT = (unsigned short*)(ws + 24*MB);  // transposed bf16 weights (2MB each)
  unsigned short* WkT = (unsigned short*)(ws + 26*MB);
  unsigned short* WvT = (unsigned short*)(ws + 28*MB);
  unsigned short* WoT = (unsigned short*)(ws + 30*MB);
  unsigned short* Qp  = (unsigned short*)(ws + 32*MB);  // projected Q (scaled), natural layout
  unsigned short* Kp  = (unsigned short*)(ws + 40*MB);  // projected K, natural layout
  unsigned short* VTb = (unsigned short*)(ws + 48*MB);  // projected V, [b][h][d][s]
  unsigned short* ctx = (unsigned short*)(ws + 56*MB);  // attention output, natural layout

  cast_qkv<<<dim3((BS*SEQ*DIM)/(256*8), 3), 256, 0, stream>>>(query, key, value, qb, kb, vb);
  wcast_t<<<dim3(DIM/32, DIM/32, 4), 256, 0, stream>>>(Wq, Wk, Wv, Wo, WqT, WkT, WvT, WoT);
  qkv_gemm<<<dim3(NWG, 3), 256, 0, stream>>>(qb, kb, vb, WqT, WkT, WvT, bq, bk, bv, Qp, Kp, VTb);
  attn<<<BS*NH*(SEQ/64), 256, 0, stream>>>(Qp, Kp, VTb, mask, gauss, ctx);
  out_gemm<<<NWG, 256, 0, stream>>>(ctx, WoT, bo, (float*)d_out);
}